// Round 3
// baseline (10408.121 us; speedup 1.0000x reference)
//
#include <hip/hip_runtime.h>
#include <cstdint>
#include <cstddef>

// ---------------------------------------------------------------------------
// FieldLstmEncoder on MI355X (gfx950)   B=128 S=512 UNI=512 HID=1024 FLD=128
// Persistent-kernel design: 256 blocks x 512 thr, one launch for all 512
// steps. Block owns 4 H-cols x 4 gates (16 N-cols). W1 h-part slice lives in
// LDS for the whole kernel. Custom grid barrier per step; x-part/field GEMM
// for step t+1 overlaps barrier propagation (h-independent prefetch).
// ---------------------------------------------------------------------------

typedef __bf16 bf16;
typedef __bf16 bf16x8 __attribute__((ext_vector_type(8)));
typedef float floatx4 __attribute__((ext_vector_type(4)));

#define B_ 128
#define S_ 512
#define UNI_ 512
#define HID_ 1024
#define FLD_ 128
#define K1_ 1536
#define NB_ 256          // persistent grid blocks
#define W1S_STRIDE 1032  // 1024 + 8 bf16 pad
#define W2S_STRIDE 136   // 128 + 8

__device__ __forceinline__ float sigf(float x) { return 1.0f / (1.0f + __expf(-x)); }

// ---------------------------------------------------------------------------
__global__ __launch_bounds__(128) void sort_kernel(const int* __restrict__ len,
                                                   int* __restrict__ perm,
                                                   int* __restrict__ lens) {
  int i = threadIdx.x;
  int li = len[i];
  int r = 0;
  for (int j = 0; j < B_; ++j) {
    int lj = len[j];
    r += (lj > li) || (lj == li && j < i) ? 1 : 0;
  }
  perm[r] = i;
  lens[r] = li;
}

__global__ __launch_bounds__(256) void conv_w(const float* __restrict__ W1,
                                              const float* __restrict__ W2,
                                              bf16* __restrict__ W1b,
                                              bf16* __restrict__ W2b) {
  int i = blockIdx.x * 256 + threadIdx.x;
  if (i < 4096 * K1_) W1b[i] = (bf16)W1[i];
  else {
    int j = i - 4096 * K1_;
    if (j < 2048 * FLD_) W2b[j] = (bf16)W2[j];
  }
}

__global__ __launch_bounds__(256) void zero_state(bf16* __restrict__ h0,
                                                  bf16* __restrict__ h1,
                                                  float* __restrict__ c,
                                                  float* __restrict__ hf,
                                                  int* __restrict__ done,
                                                  int* __restrict__ go) {
  int i = blockIdx.x * 256 + threadIdx.x;  // 131072
  h0[i] = (bf16)0.0f;
  h1[i] = (bf16)0.0f;
  c[i] = 0.0f;
  hf[i] = 0.0f;
  if (i < NB_) done[i] = 0;
  if (i == NB_) *go = 0;
}

__global__ __launch_bounds__(256) void conv_xf(const float* __restrict__ x,
                                               const float* __restrict__ f,
                                               const int* __restrict__ perm,
                                               bf16* __restrict__ xbf,
                                               bf16* __restrict__ fbf) {
  int t = blockIdx.x, rs = blockIdx.y, tid = threadIdx.x;
  int b = perm[rs];
  const float* xs = x + ((size_t)b * S_ + t) * UNI_;
  bf16* xd = xbf + ((size_t)rs * S_ + t) * UNI_;
  xd[tid] = (bf16)xs[tid];
  xd[tid + 256] = (bf16)xs[tid + 256];
  if (tid < FLD_) {
    fbf[((size_t)rs * S_ + t) * FLD_ + tid] =
        (bf16)f[((size_t)b * S_ + t) * FLD_ + tid];
  }
}

__global__ __launch_bounds__(256) void zero_tail(const int* __restrict__ len,
                                                 float* __restrict__ out) {
  int t = blockIdx.x, b = blockIdx.y;
  if (t < len[b]) return;
  float4 z = {0.0f, 0.0f, 0.0f, 0.0f};
  float4* o = (float4*)(out + ((size_t)b * S_ + t) * HID_);
  o[threadIdx.x] = z;
}

// ---------------------------------------------------------------------------
// Persistent kernel: all 512 timesteps in one launch.
// ---------------------------------------------------------------------------
__global__ __launch_bounds__(512, 2) void persist_kernel(
    const bf16* __restrict__ xbf,    // [128][S][UNI] sorted rows
    const bf16* __restrict__ fbf,    // [128][S][FLD] sorted rows
    const bf16* __restrict__ W1b,    // [4H][K1]
    const bf16* __restrict__ W2b,    // [2H][FLD]
    const float* __restrict__ bias1, const float* __restrict__ bias2,
    bf16* __restrict__ hbuf0, bf16* __restrict__ hbuf1,  // [128][HID] bf16
    float* __restrict__ c_ws, float* __restrict__ hf,    // [128][HID] fp32
    const int* __restrict__ perm_g, const int* __restrict__ lens_g,
    int* __restrict__ done, int* __restrict__ go,
    float* __restrict__ out) {
  __shared__ bf16 W1s[16 * W1S_STRIDE];  // 33.0 KB : h-part of W1 slice
  __shared__ bf16 W2s[8 * W2S_STRIDE];   //  2.2 KB
  __shared__ float pre_s[128][17];       //  8.7 KB
  __shared__ float rd_s[128][9];         //  4.6 KB
  __shared__ int lens_s[128];
  __shared__ int perm_s[128];
  __shared__ float b1_s[16];
  __shared__ float b2_s[8];

  const int tid = threadIdx.x;
  const int bid = blockIdx.x;
  const int c0 = bid * 4;  // 4 H-cols per block

  // ---- one-time staging ----
  {
    int nl = tid >> 5;  // 0..15 gate-row index
    int sg = tid & 31;
    int w1row = (nl >> 2) * HID_ + c0 + (nl & 3);
    const bf16* src = W1b + (size_t)w1row * K1_ + UNI_ + sg * 32;
    bf16* dst = W1s + nl * W1S_STRIDE + sg * 32;
#pragma unroll
    for (int p = 0; p < 4; ++p)
      *(bf16x8*)(dst + p * 8) = *(const bf16x8*)(src + p * 8);
  }
  if (tid < 128) {
    int nl = tid >> 4, sg = tid & 15;
    int w2row = (nl >> 2) * HID_ + c0 + (nl & 3);
    *(bf16x8*)(W2s + nl * W2S_STRIDE + sg * 8) =
        *(const bf16x8*)(W2b + (size_t)w2row * FLD_ + sg * 8);
  }
  if (tid < 128) { lens_s[tid] = lens_g[tid]; perm_s[tid] = perm_g[tid]; }
  if (tid < 16) b1_s[tid] = bias1[(tid >> 2) * HID_ + c0 + (tid & 3)];
  if (tid < 8) b2_s[tid] = bias2[(tid >> 2) * HID_ + c0 + (tid & 3)];
  __syncthreads();

  const int wave = tid >> 6;
  const int lane = tid & 63;
  const int quad = lane >> 4;
  const int l16 = lane & 15;
  const int kq = quad * 8;
  const int m = wave * 16 + l16;          // batch row supplied by this lane
  const int mylen = lens_s[wave * 16];    // wave active while t < mylen

  const int w1row = (l16 >> 2) * HID_ + c0 + (l16 & 3);
  const bf16* w1x = W1b + (size_t)w1row * K1_ + kq;        // x-part B (global)
  const bf16* w1h = W1s + l16 * W1S_STRIDE + kq;           // h-part B (LDS)
  const bf16* w2l = W2s + (l16 & 7) * W2S_STRIDE + kq;     // field B (LDS)
  const bf16* xrow = xbf + (size_t)m * S_ * UNI_ + kq;
  const bf16* frow = fbf + (size_t)m * S_ * FLD_ + kq;

  floatx4 acc = {0.f, 0.f, 0.f, 0.f};
  floatx4 rdacc = {0.f, 0.f, 0.f, 0.f};

  // ---- prefetch for t=0 (x-part + field; h-independent) ----
  {
    const bf16* xr = xrow;  // t=0
#pragma unroll
    for (int ki = 0; ki < 16; ++ki) {
      bf16x8 a = *(const bf16x8*)(xr + 32 * ki);
      bf16x8 b = *(const bf16x8*)(w1x + 32 * ki);
      acc = __builtin_amdgcn_mfma_f32_16x16x32_bf16(a, b, acc, 0, 0, 0);
    }
#pragma unroll
    for (int ki = 0; ki < 4; ++ki) {
      bf16x8 a = *(const bf16x8*)(frow + 32 * ki);
      bf16x8 b = *(const bf16x8*)(w2l + 32 * ki);
      rdacc = __builtin_amdgcn_mfma_f32_16x16x32_bf16(a, b, rdacc, 0, 0, 0);
    }
  }

  for (int t = 0; t < S_; ++t) {
    const bf16* h_cur = (t & 1) ? hbuf1 : hbuf0;
    bf16* h_nxt = (t & 1) ? hbuf0 : hbuf1;

    // ---- grid barrier: wait until all blocks finished step t-1 ----
    if (t > 0) {
      if (bid == 0) {
        if (tid < NB_) {
          while (__hip_atomic_load(&done[tid], __ATOMIC_RELAXED,
                                   __HIP_MEMORY_SCOPE_AGENT) < t)
            __builtin_amdgcn_s_sleep(1);
        }
        __syncthreads();
        if (tid == 0) {
          __builtin_amdgcn_fence(__ATOMIC_ACQ_REL, "agent");
          __hip_atomic_store(go, t, __ATOMIC_RELAXED, __HIP_MEMORY_SCOPE_AGENT);
        }
      } else {
        if (tid == 0) {
          while (__hip_atomic_load(go, __ATOMIC_RELAXED,
                                   __HIP_MEMORY_SCOPE_AGENT) < t)
            __builtin_amdgcn_s_sleep(1);
          __builtin_amdgcn_fence(__ATOMIC_ACQUIRE, "agent");
        }
      }
      __syncthreads();
    }

    const bool act = (t < mylen);

    // ---- h-part GEMM: A = h_prev (global), B = W1s (LDS) ----
    if (act) {
      const bf16* hr = h_cur + (size_t)m * HID_ + kq;
#pragma unroll 8
      for (int ki = 0; ki < 32; ++ki) {
        bf16x8 a = *(const bf16x8*)(hr + 32 * ki);
        bf16x8 b = *(const bf16x8*)(w1h + 32 * ki);
        acc = __builtin_amdgcn_mfma_f32_16x16x32_bf16(a, b, acc, 0, 0, 0);
      }
      // C/D: col=l16, row=quad*4+r
      const int row0 = wave * 16 + quad * 4;
#pragma unroll
      for (int r = 0; r < 4; ++r) {
        pre_s[row0 + r][l16] = acc[r];
        if (l16 < 8) rd_s[row0 + r][l16] = rdacc[r];
      }
    }
    __syncthreads();

    // ---- LSTM elementwise update: thread -> (row, col) ----
    {
      const int row = tid >> 2;
      const int cc = tid & 3;
      const int col = c0 + cc;
      const size_t sidx = (size_t)row * HID_ + col;
      if (t >= lens_s[row]) {
        h_nxt[sidx] = h_cur[sidx];  // frozen: carry across double-buffer
      } else {
        float iv = pre_s[row][cc] + b1_s[cc];
        float jv = pre_s[row][4 + cc] + b1_s[4 + cc];
        float fv = pre_s[row][8 + cc] + b1_s[8 + cc];
        float ov = pre_s[row][12 + cc] + b1_s[12 + cc];
        float rv = rd_s[row][cc] + b2_s[cc];
        float dv = rd_s[row][4 + cc] + b2_s[4 + cc];
        float cp = c_ws[sidx];
        float cn = sigf(fv + 1.0f) * cp + sigf(iv) * tanhf(jv) + sigf(rv) * tanhf(dv);
        float hn = sigf(ov) * tanhf(cn);
        out[(size_t)perm_s[row] * (S_ * HID_) + (size_t)t * HID_ + col] = hn;
        h_nxt[sidx] = (bf16)hn;
        c_ws[sidx] = cn;
        hf[sidx] = hn;
      }
    }
    __syncthreads();  // drain h_nxt stores (vmcnt0 before barrier) + protect pre_s

    // ---- arrive: signal step t complete ----
    if (tid == 0) {
      __builtin_amdgcn_fence(__ATOMIC_RELEASE, "agent");
      __hip_atomic_store(&done[bid], t + 1, __ATOMIC_RELAXED,
                         __HIP_MEMORY_SCOPE_AGENT);
    }

    // ---- prefetch step t+1 x-part + field (h-independent; hides barrier) ----
    if (t + 1 < S_) {
      acc = (floatx4){0.f, 0.f, 0.f, 0.f};
      rdacc = (floatx4){0.f, 0.f, 0.f, 0.f};
      if (t + 1 < mylen) {
        const bf16* xr = xrow + (size_t)(t + 1) * UNI_;
#pragma unroll
        for (int ki = 0; ki < 16; ++ki) {
          bf16x8 a = *(const bf16x8*)(xr + 32 * ki);
          bf16x8 b = *(const bf16x8*)(w1x + 32 * ki);
          acc = __builtin_amdgcn_mfma_f32_16x16x32_bf16(a, b, acc, 0, 0, 0);
        }
        const bf16* fr = frow + (size_t)(t + 1) * FLD_;
#pragma unroll
        for (int ki = 0; ki < 4; ++ki) {
          bf16x8 a = *(const bf16x8*)(fr + 32 * ki);
          bf16x8 b = *(const bf16x8*)(w2l + 32 * ki);
          rdacc = __builtin_amdgcn_mfma_f32_16x16x32_bf16(a, b, rdacc, 0, 0, 0);
        }
      }
    }
  }

  // ---- final (h, c) tail of d_out: block owns (all rows) x (its 4 cols) ----
  {
    const int row = tid >> 2;
    const int col = c0 + (tid & 3);
    const size_t sidx = (size_t)row * HID_ + col;
    const size_t baseH = (size_t)B_ * S_ * HID_;
    const size_t baseC = baseH + (size_t)B_ * HID_;
    out[baseH + (size_t)perm_s[row] * HID_ + col] = hf[sidx];
    out[baseC + (size_t)perm_s[row] * HID_ + col] = c_ws[sidx];
  }
}

// ---------------------------------------------------------------------------
extern "C" void kernel_launch(void* const* d_in, const int* in_sizes, int n_in,
                              void* d_out, int out_size, void* d_ws, size_t ws_size,
                              hipStream_t stream) {
  const float* x = (const float*)d_in[0];
  const float* f = (const float*)d_in[1];
  const int* len = (const int*)d_in[2];
  const float* W1 = (const float*)d_in[3];
  const float* b1 = (const float*)d_in[4];
  const float* W2 = (const float*)d_in[5];
  const float* b2 = (const float*)d_in[6];
  float* out = (float*)d_out;

  char* ws = (char*)d_ws;
  bf16* W1b = (bf16*)(ws);                // 12,582,912
  bf16* W2b = (bf16*)(ws + 12582912);     //    524,288
  bf16* xbf = (bf16*)(ws + 13107200);     // 67,108,864
  bf16* fbf = (bf16*)(ws + 80216064);     // 16,777,216
  bf16* h0 = (bf16*)(ws + 96993280);      //    262,144
  bf16* h1 = (bf16*)(ws + 97255424);      //    262,144
  float* c = (float*)(ws + 97517568);     //    524,288
  float* hf = (float*)(ws + 98041856);    //    524,288
  int* perm = (int*)(ws + 98566144);      //        512
  int* lens = (int*)(ws + 98566656);      //        512
  int* done = (int*)(ws + 98567168);      //      1,024
  int* go = (int*)(ws + 98568192);        //          4

  sort_kernel<<<1, 128, 0, stream>>>(len, perm, lens);
  conv_w<<<(4096 * K1_ + 2048 * FLD_ + 255) / 256, 256, 0, stream>>>(W1, W2, W1b, W2b);
  zero_state<<<512, 256, 0, stream>>>(h0, h1, c, hf, done, go);
  conv_xf<<<dim3(S_, B_), 256, 0, stream>>>(x, f, perm, xbf, fbf);
  zero_tail<<<dim3(S_, B_), 256, 0, stream>>>(len, out);

  persist_kernel<<<NB_, 512, 0, stream>>>(xbf, fbf, W1b, W2b, b1, b2, h0, h1, c,
                                          hf, perm, lens, done, go, out);
}